// Round 1
// baseline (13588.448 us; speedup 1.0000x reference)
//
#include <hip/hip_runtime.h>
#include <hip/hip_cooperative_groups.h>
#include <stdint.h>

namespace cg = cooperative_groups;

#define IN    64
#define H     1024
#define G4    4096      // 4*H gate rows
#define BATCH 128
#define SEQ   256
#define TLEN  96
#define KCAT  1088      // IN + H

typedef __attribute__((ext_vector_type(8))) short bf16x8;
typedef __attribute__((ext_vector_type(4))) float f32x4;

__device__ __forceinline__ unsigned short f2bf(float f) {
  union { float f; uint32_t u; } v; v.f = f;
  uint32_t u = v.u;
  return (unsigned short)((u + 0x7fffu + ((u >> 16) & 1u)) >> 16);  // RNE
}

// ---------- generic fp32 -> bf16 ----------
__global__ void k_convert(const float* __restrict__ src, unsigned short* __restrict__ dst, int n) {
  int i = blockIdx.x * blockDim.x + threadIdx.x;
  int stride = gridDim.x * blockDim.x;
  for (; i < n; i += stride) dst[i] = f2bf(src[i]);
}

// ---------- pack [Wih | Whh] gate-interleaved: packed row p=4j+g <-> torch row r=g*H+j ----------
__global__ void k_pack(const float* __restrict__ Wih, const float* __restrict__ Whh,
                       const float* __restrict__ bih, const float* __restrict__ bhh,
                       unsigned short* __restrict__ Wcat, float* __restrict__ bcat) {
  int p = blockIdx.x;                    // 0..4095
  int j = p >> 2, g = p & 3;
  int r = g * H + j;
  for (int c = threadIdx.x; c < KCAT; c += blockDim.x) {
    float v = (c < IN) ? Wih[r * IN + c] : Whh[r * H + (c - IN)];
    Wcat[(size_t)p * KCAT + c] = f2bf(v);
  }
  if (threadIdx.x == 0) bcat[p] = bih[r] + bhh[r];
}

// ---------- decoder fused weights: W_eff = Whh + Wih@lin ; b_eff = bih+bhh+Wih@lin_b ----------
__global__ void k_deceff(const float* __restrict__ Wih, const float* __restrict__ Whh,
                         const float* __restrict__ bih, const float* __restrict__ bhh,
                         const float* __restrict__ lin, const float* __restrict__ linb,
                         unsigned short* __restrict__ Weff, float* __restrict__ beff) {
  int p = blockIdx.x;
  int j = p >> 2, g = p & 3;
  int r = g * H + j;
  __shared__ float wr[IN];
  if (threadIdx.x < IN) wr[threadIdx.x] = Wih[r * IN + threadIdx.x];
  __syncthreads();
  for (int k = threadIdx.x; k < H; k += blockDim.x) {
    float acc = Whh[(size_t)r * H + k];
    #pragma unroll 8
    for (int i = 0; i < IN; ++i) acc += wr[i] * lin[(size_t)i * H + k];
    Weff[(size_t)p * H + k] = f2bf(acc);
  }
  if (threadIdx.x == 0) {
    float s = bih[r] + bhh[r];
    for (int i = 0; i < IN; ++i) s += wr[i] * linb[i];
    beff[p] = s;
  }
}

// ---------- persistent cooperative LSTM: 256 enc + 96 dec steps, 1 grid.sync()/step ----------
// 128 blocks x 512 thr. Block = 64 batch rows (mt) x 64 gate cols (nslab) = 16 hidden units.
// Wave tile 32x16: 2 MFMA 16x16x32 per K-chunk. c state in registers (fixed ownership).
__global__ __launch_bounds__(512) void k_lstm(
    const unsigned short* __restrict__ xin,
    const unsigned short* __restrict__ Wenc,  const float* __restrict__ benc,
    const unsigned short* __restrict__ Wdec0, const float* __restrict__ bdec0,
    const unsigned short* __restrict__ Wdeff, const float* __restrict__ bdeff,
    unsigned short* __restrict__ hbuf, unsigned short* __restrict__ hhist)
{
  cg::grid_group grid = cg::this_grid();
  __shared__ float zs[64 * 68];          // 64 rows x 64 cols, stride 68 (conflict pad)
  const int tid  = threadIdx.x;
  const int lane = tid & 63;
  const int wave = tid >> 6;
  const int bid  = blockIdx.x;
  // XCD-aware swizzle: XCD k owns n-slabs [8k, 8k+8) -> its weight slab stays L2-resident
  const int xcd   = bid & 7;
  const int rest  = bid >> 3;
  const int nslab = xcd * 8 + (rest & 7);   // 0..63
  const int mt    = rest >> 3;              // 0..1
  const int n0    = nslab * 64;
  const int m0    = mt * 64;
  const int rhalf = wave & 1;               // 32-row half
  const int cq    = wave >> 1;              // 16-col quarter
  const int mrow  = m0 + rhalf * 32;
  const int ncol  = n0 + cq * 16;
  const int fm    = lane & 15;              // frag row/col
  const int fk    = (lane >> 4) * 8;        // frag k offset
  const int bl0   = tid >> 4, jl = tid & 15;  // cell pairs: (bl0,jl),(bl0+32,jl)
  float cst[2] = {0.f, 0.f};
  int p = 0;
  for (int t = 0; t < SEQ + TLEN; ++t) {
    const bool is_enc = (t < SEQ);
    const unsigned short* W;
    const float* bias;
    const unsigned short* xsrc;
    int wstride, hoff;
    if (is_enc)        { W = Wenc;  bias = benc;  wstride = KCAT; hoff = IN; xsrc = xin + (size_t)t * BATCH * IN; }
    else if (t == SEQ) { W = Wdec0; bias = bdec0; wstride = KCAT; hoff = IN; xsrc = xin + (size_t)(SEQ - 1) * BATCH * IN; }
    else               { W = Wdeff; bias = bdeff; wstride = H;    hoff = 0;  xsrc = nullptr; }  // fused: pure h recurrence
    f32x4 acc0 = {0.f, 0.f, 0.f, 0.f};
    f32x4 acc1 = {0.f, 0.f, 0.f, 0.f};
    if (xsrc) {   // x segment, K=64
      const unsigned short* wb = W + (size_t)(ncol + fm) * wstride + fk;
      const unsigned short* xa = xsrc + (size_t)(mrow + fm) * IN + fk;
      #pragma unroll
      for (int kc = 0; kc < IN; kc += 32) {
        bf16x8 a0 = *(const bf16x8*)(xa + kc);
        bf16x8 a1 = *(const bf16x8*)(xa + 16 * IN + kc);
        bf16x8 b  = *(const bf16x8*)(wb + kc);
        acc0 = __builtin_amdgcn_mfma_f32_16x16x32_bf16(a0, b, acc0, 0, 0, 0);
        acc1 = __builtin_amdgcn_mfma_f32_16x16x32_bf16(a1, b, acc1, 0, 0, 0);
      }
    }
    if (t > 0) {  // h segment, K=1024 (t=0: h==0, skip)
      const unsigned short* ha = hbuf + (size_t)p * BATCH * H + (size_t)(mrow + fm) * H + fk;
      const unsigned short* wb = W + (size_t)(ncol + fm) * wstride + hoff + fk;
      #pragma unroll 4
      for (int kc = 0; kc < H; kc += 32) {
        bf16x8 a0 = *(const bf16x8*)(ha + kc);
        bf16x8 a1 = *(const bf16x8*)(ha + 16 * H + kc);
        bf16x8 b  = *(const bf16x8*)(wb + kc);
        acc0 = __builtin_amdgcn_mfma_f32_16x16x32_bf16(a0, b, acc0, 0, 0, 0);
        acc1 = __builtin_amdgcn_mfma_f32_16x16x32_bf16(a1, b, acc1, 0, 0, 0);
      }
    }
    // scatter z (D layout: col=lane&15, row=(lane>>4)*4+reg) to LDS
    {
      int colz  = cq * 16 + fm;
      int rbase = rhalf * 32 + (lane >> 4) * 4;
      #pragma unroll
      for (int j = 0; j < 4; ++j) {
        zs[(rbase + j) * 68 + colz]      = acc0[j];
        zs[(rbase + 16 + j) * 68 + colz] = acc1[j];
      }
    }
    __syncthreads();
    // fused LSTM cell: 2 (batch,unit) pairs per thread; gates i,f,g,o adjacent (interleaved pack)
    #pragma unroll
    for (int q = 0; q < 2; ++q) {
      int bl = bl0 + q * 32;
      const float4 z4 = *reinterpret_cast<const float4*>(&zs[bl * 68 + 4 * jl]);
      const float4 b4 = *reinterpret_cast<const float4*>(&bias[n0 + 4 * jl]);
      float zi = z4.x + b4.x, zf = z4.y + b4.y, zg = z4.z + b4.z, zo = z4.w + b4.w;
      float gi = 1.f / (1.f + __expf(-zi));
      float gf = 1.f / (1.f + __expf(-zf));
      float gg = tanhf(zg);
      float go = 1.f / (1.f + __expf(-zo));
      float c  = gf * cst[q] + gi * gg;
      cst[q] = c;
      float h = go * tanhf(c);
      unsigned short hb = f2bf(h);
      int hidx = (m0 + bl) * H + (n0 >> 2) + jl;
      hbuf[(size_t)(1 - p) * BATCH * H + hidx] = hb;
      if (!is_enc) hhist[(size_t)(t - SEQ) * BATCH * H + hidx] = hb;
    }
    p ^= 1;
    if (t + 1 < SEQ + TLEN) grid.sync();
  }
}

// ---------- epilogue: all 96 outputs in one GEMM  y = hhist @ lin^T + lin_b ----------
// M=96*128=12288, N=64, K=1024. 192 blocks x 256 thr; wave tile 16x64.
__global__ __launch_bounds__(256) void k_out(
    const unsigned short* __restrict__ hhist, const unsigned short* __restrict__ linb16,
    const float* __restrict__ linb, float* __restrict__ out)
{
  const int tid  = threadIdx.x;
  const int lane = tid & 63;
  const int wave = tid >> 6;
  const int fm   = lane & 15;
  const int fk   = (lane >> 4) * 8;
  const int R0   = blockIdx.x * 64 + wave * 16;
  f32x4 acc[4] = {{0.f,0.f,0.f,0.f},{0.f,0.f,0.f,0.f},{0.f,0.f,0.f,0.f},{0.f,0.f,0.f,0.f}};
  const unsigned short* ha = hhist + (size_t)(R0 + fm) * H + fk;
  #pragma unroll 2
  for (int kc = 0; kc < H; kc += 32) {
    bf16x8 a = *(const bf16x8*)(ha + kc);
    #pragma unroll
    for (int nq = 0; nq < 4; ++nq) {
      bf16x8 b = *(const bf16x8*)(linb16 + (size_t)(nq * 16 + fm) * H + fk + kc);
      acc[nq] = __builtin_amdgcn_mfma_f32_16x16x32_bf16(a, b, acc[nq], 0, 0, 0);
    }
  }
  #pragma unroll
  for (int nq = 0; nq < 4; ++nq) {
    int col = nq * 16 + fm;
    float bb = linb[col];
    #pragma unroll
    for (int j = 0; j < 4; ++j) {
      int R = R0 + (lane >> 4) * 4 + j;
      out[(size_t)R * IN + col] = acc[nq][j] + bb;
    }
  }
}

extern "C" void kernel_launch(void* const* d_in, const int* in_sizes, int n_in,
                              void* d_out, int out_size, void* d_ws, size_t ws_size,
                              hipStream_t stream) {
  const float* input_batch = (const float*)d_in[0];
  // d_in[1] target_batch: unused (no teacher forcing)
  const float* eWih = (const float*)d_in[2];
  const float* eWhh = (const float*)d_in[3];
  const float* ebih = (const float*)d_in[4];
  const float* ebhh = (const float*)d_in[5];
  const float* dWih = (const float*)d_in[6];
  const float* dWhh = (const float*)d_in[7];
  const float* dbih = (const float*)d_in[8];
  const float* dbhh = (const float*)d_in[9];
  const float* linW = (const float*)d_in[10];
  const float* linb = (const float*)d_in[11];
  float* out = (float*)d_out;

  char* ws = (char*)d_ws;
  size_t off = 0;
  auto alloc = [&](size_t bytes) -> void* {
    void* pp = ws + off;
    off = (off + bytes + 255) & ~(size_t)255;
    return pp;
  };
  unsigned short* xin   = (unsigned short*)alloc((size_t)SEQ * BATCH * IN * 2);
  unsigned short* Wenc  = (unsigned short*)alloc((size_t)G4 * KCAT * 2);
  float*          benc  = (float*)         alloc((size_t)G4 * 4);
  unsigned short* Wdec0 = (unsigned short*)alloc((size_t)G4 * KCAT * 2);
  float*          bdec0 = (float*)         alloc((size_t)G4 * 4);
  unsigned short* Wdeff = (unsigned short*)alloc((size_t)G4 * H * 2);
  float*          bdeff = (float*)         alloc((size_t)G4 * 4);
  unsigned short* linbf = (unsigned short*)alloc((size_t)IN * H * 2);
  unsigned short* hbuf  = (unsigned short*)alloc((size_t)2 * BATCH * H * 2);
  unsigned short* hhist = (unsigned short*)alloc((size_t)TLEN * BATCH * H * 2);
  (void)ws_size; (void)in_sizes; (void)n_in; (void)out_size;

  hipLaunchKernelGGL(k_convert, dim3(512), dim3(256), 0, stream, input_batch, xin, SEQ * BATCH * IN);
  hipLaunchKernelGGL(k_convert, dim3(64),  dim3(256), 0, stream, linW, linbf, IN * H);
  hipLaunchKernelGGL(k_pack,   dim3(G4), dim3(256), 0, stream, eWih, eWhh, ebih, ebhh, Wenc, benc);
  hipLaunchKernelGGL(k_pack,   dim3(G4), dim3(256), 0, stream, dWih, dWhh, dbih, dbhh, Wdec0, bdec0);
  hipLaunchKernelGGL(k_deceff, dim3(G4), dim3(256), 0, stream, dWih, dWhh, dbih, dbhh, linW, linb, Wdeff, bdeff);

  void* args[] = { &xin, &Wenc, &benc, &Wdec0, &bdec0, &Wdeff, &bdeff, &hbuf, &hhist };
  hipLaunchCooperativeKernel((void*)k_lstm, dim3(128), dim3(512), args, 0, stream);

  hipLaunchKernelGGL(k_out, dim3((TLEN * BATCH) / 64), dim3(256), 0, stream, hhist, linbf, linb, out);
}

// Round 2
// 8583.575 us; speedup vs baseline: 1.5831x; 1.5831x over previous
//
#include <hip/hip_runtime.h>
#include <stdint.h>

#define IN    64
#define H     1024
#define G4    4096      // 4*H gate rows
#define BATCH 128
#define SEQ   256
#define TLEN  96
#define KCAT  1088      // IN + H
#define NSTEP (SEQ + TLEN)
#define NBLK  256

typedef __attribute__((ext_vector_type(8))) short bf16x8;
typedef __attribute__((ext_vector_type(4))) float f32x4;

__device__ __forceinline__ unsigned short f2bf(float f) {
  union { float f; uint32_t u; } v; v.f = f;
  uint32_t u = v.u;
  return (unsigned short)((u + 0x7fffu + ((u >> 16) & 1u)) >> 16);  // RNE
}

// ---------- generic fp32 -> bf16 ----------
__global__ void k_convert(const float* __restrict__ src, unsigned short* __restrict__ dst, int n) {
  int i = blockIdx.x * blockDim.x + threadIdx.x;
  int stride = gridDim.x * blockDim.x;
  for (; i < n; i += stride) dst[i] = f2bf(src[i]);
}

// ---------- pack [Wih | Whh] gate-interleaved: packed row p=4j+g <-> torch row r=g*H+j ----------
__global__ void k_pack(const float* __restrict__ Wih, const float* __restrict__ Whh,
                       const float* __restrict__ bih, const float* __restrict__ bhh,
                       unsigned short* __restrict__ Wcat, float* __restrict__ bcat) {
  int p = blockIdx.x;                    // 0..4095
  int j = p >> 2, g = p & 3;
  int r = g * H + j;
  for (int c = threadIdx.x; c < KCAT; c += blockDim.x) {
    float v = (c < IN) ? Wih[r * IN + c] : Whh[r * H + (c - IN)];
    Wcat[(size_t)p * KCAT + c] = f2bf(v);
  }
  if (threadIdx.x == 0) bcat[p] = bih[r] + bhh[r];
}

// ---------- decoder fused weights: W_eff = Whh + Wih@lin ; b_eff = bih+bhh+Wih@lin_b ----------
__global__ void k_deceff(const float* __restrict__ Wih, const float* __restrict__ Whh,
                         const float* __restrict__ bih, const float* __restrict__ bhh,
                         const float* __restrict__ lin, const float* __restrict__ linb,
                         unsigned short* __restrict__ Weff, float* __restrict__ beff) {
  int p = blockIdx.x;
  int j = p >> 2, g = p & 3;
  int r = g * H + j;
  __shared__ float wr[IN];
  if (threadIdx.x < IN) wr[threadIdx.x] = Wih[r * IN + threadIdx.x];
  __syncthreads();
  for (int k = threadIdx.x; k < H; k += blockDim.x) {
    float acc = Whh[(size_t)r * H + k];
    #pragma unroll 8
    for (int i = 0; i < IN; ++i) acc += wr[i] * lin[(size_t)i * H + k];
    Weff[(size_t)p * H + k] = f2bf(acc);
  }
  if (threadIdx.x == 0) {
    float s = bih[r] + bhh[r];
    for (int i = 0; i < IN; ++i) s += wr[i] * linb[i];
    beff[p] = s;
  }
}

// h loads bypass L1/L2 (agent-scope atomic -> sc0 sc1), read die-coherent L3 directly.
__device__ __forceinline__ bf16x8 ld_bypass16(const unsigned short* p) {
  union { unsigned long long q[2]; bf16x8 v; } u;
  u.q[0] = __hip_atomic_load((unsigned long long*)p,       __ATOMIC_RELAXED, __HIP_MEMORY_SCOPE_AGENT);
  u.q[1] = __hip_atomic_load((unsigned long long*)(p + 4), __ATOMIC_RELAXED, __HIP_MEMORY_SCOPE_AGENT);
  return u.v;
}

// ---------- persistent LSTM: 256 enc + 96 dec steps, fence-free epoch barrier ----------
// 256 blocks x 512 thr. Block = 32 batch rows x 64 gate cols (16 hidden units).
// 8 waves = 2 row-groups x 4 col-groups; wave tile 16x16, K-loop 32 MFMA.
// h path: sc0/sc1 (agent atomics) through L3 -> no L2 fences ever -> weights stay L2-resident.
__global__ __launch_bounds__(512) void k_lstm(
    const unsigned short* __restrict__ xin,
    const unsigned short* __restrict__ Wenc,  const float* __restrict__ benc,
    const unsigned short* __restrict__ Wdec0, const float* __restrict__ bdec0,
    const unsigned short* __restrict__ Wdeff, const float* __restrict__ bdeff,
    unsigned short* __restrict__ hbuf, unsigned short* __restrict__ hhist,
    unsigned int* __restrict__ flags)
{
  __shared__ float zs[32 * 68];          // 32 rows x 64 cols, stride 68 (conflict pad)
  const int tid  = threadIdx.x;
  const int lane = tid & 63;
  const int wave = tid >> 6;             // 0..7
  const int bid  = blockIdx.x;           // 0..255
  // XCD swizzle: XCD k owns n-slabs [8k,8k+8) for all 4 m-tiles -> 1.1 MB weights L2-resident
  const int xcd   = bid & 7;
  const int rest  = bid >> 3;            // 0..31
  const int nslab = xcd * 8 + (rest & 7);  // 0..63
  const int mt    = rest >> 3;             // 0..3
  const int n0    = nslab * 64;
  const int m0    = mt * 32;
  const int rowg  = wave >> 2;           // 0..1
  const int colg  = wave & 3;            // 0..3
  const int mrow  = m0 + rowg * 16;
  const int ncol  = n0 + colg * 16;
  const int fm    = lane & 15;
  const int fk    = (lane >> 4) * 8;
  const int crow  = tid >> 4;            // cell: batch row 0..31
  const int cu    = tid & 15;            // cell: hidden unit 0..15
  float cst = 0.f;
  int p = 0;
  for (int t = 0; t < NSTEP; ++t) {
    const bool is_enc = (t < SEQ);
    const unsigned short* W;
    const float* bias;
    const unsigned short* xsrc;
    int wstride, hoff;
    if (is_enc)        { W = Wenc;  bias = benc;  wstride = KCAT; hoff = IN; xsrc = xin + (size_t)t * BATCH * IN; }
    else if (t == SEQ) { W = Wdec0; bias = bdec0; wstride = KCAT; hoff = IN; xsrc = xin + (size_t)(SEQ - 1) * BATCH * IN; }
    else               { W = Wdeff; bias = bdeff; wstride = H;    hoff = 0;  xsrc = nullptr; }  // fused: pure h recurrence
    f32x4 acc = {0.f, 0.f, 0.f, 0.f};
    if (xsrc) {   // x segment, K=64 (cached loads, xin is static)
      const unsigned short* wb = W + (size_t)(ncol + fm) * wstride + fk;
      const unsigned short* xa = xsrc + (size_t)(mrow + fm) * IN + fk;
      #pragma unroll
      for (int kc = 0; kc < IN; kc += 32) {
        bf16x8 a = *(const bf16x8*)(xa + kc);
        bf16x8 b = *(const bf16x8*)(wb + kc);
        acc = __builtin_amdgcn_mfma_f32_16x16x32_bf16(a, b, acc, 0, 0, 0);
      }
    }
    if (t > 0) {  // h segment, K=1024 (t=0: h==0, skip); A via L3-coherent bypass loads
      const unsigned short* ha = hbuf + (size_t)p * BATCH * H + (size_t)(mrow + fm) * H + fk;
      const unsigned short* wb = W + (size_t)(ncol + fm) * wstride + hoff + fk;
      #pragma unroll 8
      for (int kc = 0; kc < H; kc += 32) {
        bf16x8 a = ld_bypass16(ha + kc);
        bf16x8 b = *(const bf16x8*)(wb + kc);
        acc = __builtin_amdgcn_mfma_f32_16x16x32_bf16(a, b, acc, 0, 0, 0);
      }
    }
    // scatter z (D layout: col=lane&15, row=(lane>>4)*4+reg) to LDS
    {
      int colz  = colg * 16 + fm;
      int rbase = rowg * 16 + (lane >> 4) * 4;
      #pragma unroll
      for (int j = 0; j < 4; ++j) zs[(rbase + j) * 68 + colz] = acc[j];
    }
    __syncthreads();
    // fused LSTM cell: 1 (batch,unit) per thread; gates i,f,g,o adjacent (interleaved pack)
    {
      const float4 z4 = *reinterpret_cast<const float4*>(&zs[crow * 68 + 4 * cu]);
      const float4 b4 = *reinterpret_cast<const float4*>(&bias[n0 + 4 * cu]);
      float zi = z4.x + b4.x, zf = z4.y + b4.y, zg = z4.z + b4.z, zo = z4.w + b4.w;
      float gi = 1.f / (1.f + __expf(-zi));
      float gf = 1.f / (1.f + __expf(-zf));
      float gg = tanhf(zg);
      float go = 1.f / (1.f + __expf(-zo));
      float c  = gf * cst + gi * gg;
      cst = c;
      float h = go * tanhf(c);
      unsigned hv = (unsigned)f2bf(h);
      unsigned ov = __shfl_xor(hv, 1);           // pair adjacent units -> one 4B store
      if ((cu & 1) == 0) {
        unsigned pk = (hv & 0xffffu) | (ov << 16);
        size_t base = (size_t)(m0 + crow) * H + (n0 >> 2) + cu;
        __hip_atomic_store((unsigned*)(hbuf + (size_t)(1 - p) * BATCH * H + base), pk,
                           __ATOMIC_RELAXED, __HIP_MEMORY_SCOPE_AGENT);
        if (!is_enc) *(unsigned*)(hhist + (size_t)(t - SEQ) * BATCH * H + base) = pk;
      }
    }
    p ^= 1;
    if (t + 1 < NSTEP) {
      // epoch barrier: __syncthreads drains this block's h stores (compiler emits
      // s_waitcnt vmcnt(0) before s_barrier); flags are monotonic epochs, 0xAA-safe
      // because they are memset to 0 before launch and compared with >=.
      __syncthreads();
      if (tid == 0)
        __hip_atomic_store(&flags[bid * 16], (unsigned)(t + 1), __ATOMIC_RELAXED, __HIP_MEMORY_SCOPE_AGENT);
      if (tid < NBLK) {
        while (__hip_atomic_load(&flags[tid * 16], __ATOMIC_RELAXED, __HIP_MEMORY_SCOPE_AGENT) < (unsigned)(t + 1))
          __builtin_amdgcn_s_sleep(1);
      }
      __syncthreads();
    }
  }
}

// ---------- epilogue: all 96 outputs in one GEMM  y = hhist @ lin^T + lin_b ----------
__global__ __launch_bounds__(256) void k_out(
    const unsigned short* __restrict__ hhist, const unsigned short* __restrict__ linb16,
    const float* __restrict__ linb, float* __restrict__ out)
{
  const int tid  = threadIdx.x;
  const int lane = tid & 63;
  const int wave = tid >> 6;
  const int fm   = lane & 15;
  const int fk   = (lane >> 4) * 8;
  const int R0   = blockIdx.x * 64 + wave * 16;
  f32x4 acc[4] = {{0.f,0.f,0.f,0.f},{0.f,0.f,0.f,0.f},{0.f,0.f,0.f,0.f},{0.f,0.f,0.f,0.f}};
  const unsigned short* ha = hhist + (size_t)(R0 + fm) * H + fk;
  #pragma unroll 2
  for (int kc = 0; kc < H; kc += 32) {
    bf16x8 a = *(const bf16x8*)(ha + kc);
    #pragma unroll
    for (int nq = 0; nq < 4; ++nq) {
      bf16x8 b = *(const bf16x8*)(linb16 + (size_t)(nq * 16 + fm) * H + fk + kc);
      acc[nq] = __builtin_amdgcn_mfma_f32_16x16x32_bf16(a, b, acc[nq], 0, 0, 0);
    }
  }
  #pragma unroll
  for (int nq = 0; nq < 4; ++nq) {
    int col = nq * 16 + fm;
    float bb = linb[col];
    #pragma unroll
    for (int j = 0; j < 4; ++j) {
      int R = R0 + (lane >> 4) * 4 + j;
      out[(size_t)R * IN + col] = acc[nq][j] + bb;
    }
  }
}

extern "C" void kernel_launch(void* const* d_in, const int* in_sizes, int n_in,
                              void* d_out, int out_size, void* d_ws, size_t ws_size,
                              hipStream_t stream) {
  const float* input_batch = (const float*)d_in[0];
  // d_in[1] target_batch: unused (no teacher forcing)
  const float* eWih = (const float*)d_in[2];
  const float* eWhh = (const float*)d_in[3];
  const float* ebih = (const float*)d_in[4];
  const float* ebhh = (const float*)d_in[5];
  const float* dWih = (const float*)d_in[6];
  const float* dWhh = (const float*)d_in[7];
  const float* dbih = (const float*)d_in[8];
  const float* dbhh = (const float*)d_in[9];
  const float* linW = (const float*)d_in[10];
  const float* linb = (const float*)d_in[11];
  float* out = (float*)d_out;

  char* ws = (char*)d_ws;
  size_t off = 0;
  auto alloc = [&](size_t bytes) -> void* {
    void* pp = ws + off;
    off = (off + bytes + 255) & ~(size_t)255;
    return pp;
  };
  unsigned short* xin   = (unsigned short*)alloc((size_t)SEQ * BATCH * IN * 2);
  unsigned short* Wenc  = (unsigned short*)alloc((size_t)G4 * KCAT * 2);
  float*          benc  = (float*)         alloc((size_t)G4 * 4);
  unsigned short* Wdec0 = (unsigned short*)alloc((size_t)G4 * KCAT * 2);
  float*          bdec0 = (float*)         alloc((size_t)G4 * 4);
  unsigned short* Wdeff = (unsigned short*)alloc((size_t)G4 * H * 2);
  float*          bdeff = (float*)         alloc((size_t)G4 * 4);
  unsigned short* linbf = (unsigned short*)alloc((size_t)IN * H * 2);
  unsigned short* hbuf  = (unsigned short*)alloc((size_t)2 * BATCH * H * 2);
  unsigned short* hhist = (unsigned short*)alloc((size_t)TLEN * BATCH * H * 2);
  unsigned int*   flags = (unsigned int*)  alloc((size_t)NBLK * 16 * sizeof(unsigned));
  (void)ws_size; (void)in_sizes; (void)n_in; (void)out_size;

  hipMemsetAsync(flags, 0, (size_t)NBLK * 16 * sizeof(unsigned), stream);
  hipLaunchKernelGGL(k_convert, dim3(512), dim3(256), 0, stream, input_batch, xin, SEQ * BATCH * IN);
  hipLaunchKernelGGL(k_convert, dim3(64),  dim3(256), 0, stream, linW, linbf, IN * H);
  hipLaunchKernelGGL(k_pack,   dim3(G4), dim3(256), 0, stream, eWih, eWhh, ebih, ebhh, Wenc, benc);
  hipLaunchKernelGGL(k_pack,   dim3(G4), dim3(256), 0, stream, dWih, dWhh, dbih, dbhh, Wdec0, bdec0);
  hipLaunchKernelGGL(k_deceff, dim3(G4), dim3(256), 0, stream, dWih, dWhh, dbih, dbhh, linW, linb, Wdeff, bdeff);

  void* args[] = { &xin, &Wenc, &benc, &Wdec0, &bdec0, &Wdeff, &bdeff, &hbuf, &hhist, &flags };
  hipLaunchCooperativeKernel((void*)k_lstm, dim3(NBLK), dim3(512), args, 0, stream);

  hipLaunchKernelGGL(k_out, dim3((TLEN * BATCH) / 64), dim3(256), 0, stream, hhist, linbf, linb, out);
}

// Round 3
// 6627.727 us; speedup vs baseline: 2.0502x; 1.2951x over previous
//
#include <hip/hip_runtime.h>
#include <stdint.h>

#define IN    64
#define H     1024
#define G4    4096      // 4*H gate rows
#define BATCH 128
#define SEQ   256
#define TLEN  96
#define KCAT  1088      // IN + H
#define NSTEP (SEQ + TLEN)
#define NBLK  128
#define HPAD  1032      // h row stride in LDS (bf16), +8 pad for bank spread

typedef __attribute__((ext_vector_type(8))) short bf16x8;
typedef __attribute__((ext_vector_type(4))) float f32x4;

__device__ __forceinline__ unsigned short f2bf(float f) {
  union { float f; uint32_t u; } v; v.f = f;
  uint32_t u = v.u;
  return (unsigned short)((u + 0x7fffu + ((u >> 16) & 1u)) >> 16);  // RNE
}

// ---------- generic fp32 -> bf16 ----------
__global__ void k_convert(const float* __restrict__ src, unsigned short* __restrict__ dst, int n) {
  int i = blockIdx.x * blockDim.x + threadIdx.x;
  int stride = gridDim.x * blockDim.x;
  for (; i < n; i += stride) dst[i] = f2bf(src[i]);
}

// ---------- pack [Wih | Whh] gate-interleaved: packed row p=4j+g <-> torch row r=g*H+j ----------
__global__ void k_pack(const float* __restrict__ Wih, const float* __restrict__ Whh,
                       const float* __restrict__ bih, const float* __restrict__ bhh,
                       unsigned short* __restrict__ Wcat, float* __restrict__ bcat) {
  int p = blockIdx.x;                    // 0..4095
  int j = p >> 2, g = p & 3;
  int r = g * H + j;
  for (int c = threadIdx.x; c < KCAT; c += blockDim.x) {
    float v = (c < IN) ? Wih[r * IN + c] : Whh[r * H + (c - IN)];
    Wcat[(size_t)p * KCAT + c] = f2bf(v);
  }
  if (threadIdx.x == 0) bcat[p] = bih[r] + bhh[r];
}

// ---------- decoder fused weights: W_eff = Whh + Wih@lin ; b_eff = bih+bhh+Wih@lin_b ----------
__global__ void k_deceff(const float* __restrict__ Wih, const float* __restrict__ Whh,
                         const float* __restrict__ bih, const float* __restrict__ bhh,
                         const float* __restrict__ lin, const float* __restrict__ linb,
                         unsigned short* __restrict__ Weff, float* __restrict__ beff) {
  int p = blockIdx.x;
  int j = p >> 2, g = p & 3;
  int r = g * H + j;
  __shared__ float wr[IN];
  if (threadIdx.x < IN) wr[threadIdx.x] = Wih[r * IN + threadIdx.x];
  __syncthreads();
  for (int k = threadIdx.x; k < H; k += blockDim.x) {
    float acc = Whh[(size_t)r * H + k];
    #pragma unroll 8
    for (int i = 0; i < IN; ++i) acc += wr[i] * lin[(size_t)i * H + k];
    Weff[(size_t)p * H + k] = f2bf(acc);
  }
  if (threadIdx.x == 0) {
    float s = bih[r] + bhh[r];
    for (int i = 0; i < IN; ++i) s += wr[i] * linb[i];
    beff[p] = s;
  }
}

// h loads bypass L1/L2 (agent-scope atomic), served at the die-coherent point.
__device__ __forceinline__ bf16x8 ld_bypass16(const unsigned short* p) {
  union { unsigned long long q[2]; bf16x8 v; } u;
  u.q[0] = __hip_atomic_load((unsigned long long*)p,       __ATOMIC_RELAXED, __HIP_MEMORY_SCOPE_AGENT);
  u.q[1] = __hip_atomic_load((unsigned long long*)(p + 4), __ATOMIC_RELAXED, __HIP_MEMORY_SCOPE_AGENT);
  return u.v;
}

// ---------- persistent LSTM: 256 enc + 96 dec steps, fence-free epoch barrier ----------
// 128 blocks x 512 thr. Block = 16 batch rows x 256 gates (rt=bid>>4, ct=bid&15).
// bid%8 == ct%8 -> XCD k holds col-tiles {k, k+8}: 1.1 MB weight slab L2-resident.
// h is bypass-read ONCE per block (32 KB) into LDS; all 8 waves read A-frags from LDS.
// Bypass traffic/step: 128 x 32 KB = 4 MB (was 64 MB in R2).
__global__ __launch_bounds__(512) void k_lstm(
    const unsigned short* __restrict__ xin,
    const unsigned short* __restrict__ Wenc,  const float* __restrict__ benc,
    const unsigned short* __restrict__ Wdec0, const float* __restrict__ bdec0,
    const unsigned short* __restrict__ Wdeff, const float* __restrict__ bdeff,
    unsigned short* __restrict__ hbuf, unsigned short* __restrict__ hhist,
    unsigned int* __restrict__ flags)
{
  __shared__ unsigned short hs[16 * HPAD];   // staged h tile: 16 rows x 1024 (+8 pad)
  __shared__ float zs[16 * 260];             // z tile: 16 rows x 256 gates (+4 pad)
  const int tid  = threadIdx.x;
  const int lane = tid & 63;
  const int wave = tid >> 6;             // 0..7
  const int bid  = blockIdx.x;           // 0..127
  const int ct   = bid & 15;             // col-tile 0..15 (256 gates)
  const int rt   = bid >> 4;             // row-tile 0..7  (16 batch rows)
  const int n0   = ct * 256;
  const int m0   = rt * 16;
  const int u0   = n0 >> 2;              // first hidden unit of this tile
  const int gw   = n0 + wave * 32;       // this wave's 32 gate cols
  const int fm   = lane & 15;
  const int fk   = (lane >> 4) * 8;
  const int crow = tid >> 5;             // cell: batch row 0..15
  const int iu   = tid & 31;             // cell: unit-pair index 0..31
  float cst[2] = {0.f, 0.f};
  int p = 0;
  for (int t = 0; t < NSTEP; ++t) {
    const bool is_enc = (t < SEQ);
    const unsigned short* W;
    const float* bias;
    const unsigned short* xsrc;
    int wstride, hoff;
    if (is_enc)        { W = Wenc;  bias = benc;  wstride = KCAT; hoff = IN; xsrc = xin + (size_t)t * BATCH * IN; }
    else if (t == SEQ) { W = Wdec0; bias = bdec0; wstride = KCAT; hoff = IN; xsrc = xin + (size_t)(SEQ - 1) * BATCH * IN; }
    else               { W = Wdeff; bias = bdeff; wstride = H;    hoff = 0;  xsrc = nullptr; }  // fused: pure h recurrence
    // ---- stage h(t) tile (16 rows x 1024) into LDS: one bypass read per element ----
    if (t > 0) {
      const unsigned short* hbase = hbuf + (size_t)p * BATCH * H + (size_t)m0 * H;
      #pragma unroll
      for (int it = 0; it < 4; ++it) {
        int i   = tid + it * 512;        // 0..2047 16B-chunks
        int row = i >> 7;
        int cc  = (i & 127) * 8;
        bf16x8 v = ld_bypass16(hbase + (size_t)row * H + cc);
        *(bf16x8*)(&hs[row * HPAD + cc]) = v;
      }
      __syncthreads();
    }
    f32x4 acc0 = {0.f, 0.f, 0.f, 0.f};
    f32x4 acc1 = {0.f, 0.f, 0.f, 0.f};
    if (xsrc) {   // x segment, K=64 (cached loads, xin static)
      const unsigned short* xa  = xsrc + (size_t)(m0 + fm) * IN + fk;
      const unsigned short* wb0 = W + (size_t)(gw + fm) * wstride + fk;
      const unsigned short* wb1 = W + (size_t)(gw + 16 + fm) * wstride + fk;
      #pragma unroll
      for (int kc = 0; kc < IN; kc += 32) {
        bf16x8 a  = *(const bf16x8*)(xa + kc);
        acc0 = __builtin_amdgcn_mfma_f32_16x16x32_bf16(a, *(const bf16x8*)(wb0 + kc), acc0, 0, 0, 0);
        acc1 = __builtin_amdgcn_mfma_f32_16x16x32_bf16(a, *(const bf16x8*)(wb1 + kc), acc1, 0, 0, 0);
      }
    }
    if (t > 0) {  // h segment, K=1024; A from LDS (shared by all waves), B streams from L2
      const unsigned short* wb0 = W + (size_t)(gw + fm) * wstride + hoff + fk;
      const unsigned short* wb1 = W + (size_t)(gw + 16 + fm) * wstride + hoff + fk;
      const unsigned short* as  = &hs[fm * HPAD + fk];
      #pragma unroll 8
      for (int kc = 0; kc < H; kc += 32) {
        bf16x8 a = *(const bf16x8*)(as + kc);
        acc0 = __builtin_amdgcn_mfma_f32_16x16x32_bf16(a, *(const bf16x8*)(wb0 + kc), acc0, 0, 0, 0);
        acc1 = __builtin_amdgcn_mfma_f32_16x16x32_bf16(a, *(const bf16x8*)(wb1 + kc), acc1, 0, 0, 0);
      }
    }
    // scatter z (D layout: col=lane&15, row=(lane>>4)*4+reg); waves write disjoint col ranges
    {
      int rbase = (lane >> 4) * 4;
      int c0 = wave * 32 + fm;
      #pragma unroll
      for (int j = 0; j < 4; ++j) {
        zs[(rbase + j) * 260 + c0]      = acc0[j];
        zs[(rbase + j) * 260 + c0 + 16] = acc1[j];
      }
    }
    __syncthreads();
    // fused LSTM cell: 2 adjacent units per thread (gates i,f,g,o interleaved)
    {
      const float4* zp = (const float4*)&zs[crow * 260 + 8 * iu];
      const float4* bp = (const float4*)&bias[n0 + 8 * iu];
      unsigned pk = 0;
      #pragma unroll
      for (int q = 0; q < 2; ++q) {
        float4 z4 = zp[q], b4 = bp[q];
        float zi = z4.x + b4.x, zf = z4.y + b4.y, zg = z4.z + b4.z, zo = z4.w + b4.w;
        float gi = 1.f / (1.f + __expf(-zi));
        float gf = 1.f / (1.f + __expf(-zf));
        float gg = tanhf(zg);
        float go = 1.f / (1.f + __expf(-zo));
        float c  = gf * cst[q] + gi * gg;
        cst[q] = c;
        float h = go * tanhf(c);
        pk |= ((unsigned)f2bf(h)) << (16 * q);
      }
      size_t base = (size_t)(m0 + crow) * H + u0 + 2 * iu;
      __hip_atomic_store((unsigned*)(hbuf + (size_t)(1 - p) * BATCH * H + base), pk,
                         __ATOMIC_RELAXED, __HIP_MEMORY_SCOPE_AGENT);
      if (!is_enc) *(unsigned*)(hhist + (size_t)(t - SEQ) * BATCH * H + base) = pk;
    }
    p ^= 1;
    if (t + 1 < NSTEP) {
      // epoch barrier: __syncthreads drains h stores (vmcnt(0) before s_barrier),
      // then monotonic per-block epoch flags (memset to 0 pre-launch, compared >=).
      __syncthreads();
      if (tid == 0)
        __hip_atomic_store(&flags[bid * 16], (unsigned)(t + 1), __ATOMIC_RELAXED, __HIP_MEMORY_SCOPE_AGENT);
      if (tid < NBLK) {
        while (__hip_atomic_load(&flags[tid * 16], __ATOMIC_RELAXED, __HIP_MEMORY_SCOPE_AGENT) < (unsigned)(t + 1))
          __builtin_amdgcn_s_sleep(1);
      }
      __syncthreads();
    }
  }
}

// ---------- epilogue: all 96 outputs in one GEMM  y = hhist @ lin^T + lin_b ----------
__global__ __launch_bounds__(256) void k_out(
    const unsigned short* __restrict__ hhist, const unsigned short* __restrict__ linb16,
    const float* __restrict__ linb, float* __restrict__ out)
{
  const int tid  = threadIdx.x;
  const int lane = tid & 63;
  const int wave = tid >> 6;
  const int fm   = lane & 15;
  const int fk   = (lane >> 4) * 8;
  const int R0   = blockIdx.x * 64 + wave * 16;
  f32x4 acc[4] = {{0.f,0.f,0.f,0.f},{0.f,0.f,0.f,0.f},{0.f,0.f,0.f,0.f},{0.f,0.f,0.f,0.f}};
  const unsigned short* ha = hhist + (size_t)(R0 + fm) * H + fk;
  #pragma unroll 2
  for (int kc = 0; kc < H; kc += 32) {
    bf16x8 a = *(const bf16x8*)(ha + kc);
    #pragma unroll
    for (int nq = 0; nq < 4; ++nq) {
      bf16x8 b = *(const bf16x8*)(linb16 + (size_t)(nq * 16 + fm) * H + fk + kc);
      acc[nq] = __builtin_amdgcn_mfma_f32_16x16x32_bf16(a, b, acc[nq], 0, 0, 0);
    }
  }
  #pragma unroll
  for (int nq = 0; nq < 4; ++nq) {
    int col = nq * 16 + fm;
    float bb = linb[col];
    #pragma unroll
    for (int j = 0; j < 4; ++j) {
      int R = R0 + (lane >> 4) * 4 + j;
      out[(size_t)R * IN + col] = acc[nq][j] + bb;
    }
  }
}

extern "C" void kernel_launch(void* const* d_in, const int* in_sizes, int n_in,
                              void* d_out, int out_size, void* d_ws, size_t ws_size,
                              hipStream_t stream) {
  const float* input_batch = (const float*)d_in[0];
  // d_in[1] target_batch: unused (no teacher forcing)
  const float* eWih = (const float*)d_in[2];
  const float* eWhh = (const float*)d_in[3];
  const float* ebih = (const float*)d_in[4];
  const float* ebhh = (const float*)d_in[5];
  const float* dWih = (const float*)d_in[6];
  const float* dWhh = (const float*)d_in[7];
  const float* dbih = (const float*)d_in[8];
  const float* dbhh = (const float*)d_in[9];
  const float* linW = (const float*)d_in[10];
  const float* linb = (const float*)d_in[11];
  float* out = (float*)d_out;

  char* ws = (char*)d_ws;
  size_t off = 0;
  auto alloc = [&](size_t bytes) -> void* {
    void* pp = ws + off;
    off = (off + bytes + 255) & ~(size_t)255;
    return pp;
  };
  unsigned short* xin   = (unsigned short*)alloc((size_t)SEQ * BATCH * IN * 2);
  unsigned short* Wenc  = (unsigned short*)alloc((size_t)G4 * KCAT * 2);
  float*          benc  = (float*)         alloc((size_t)G4 * 4);
  unsigned short* Wdec0 = (unsigned short*)alloc((size_t)G4 * KCAT * 2);
  float*          bdec0 = (float*)         alloc((size_t)G4 * 4);
  unsigned short* Wdeff = (unsigned short*)alloc((size_t)G4 * H * 2);
  float*          bdeff = (float*)         alloc((size_t)G4 * 4);
  unsigned short* linbf = (unsigned short*)alloc((size_t)IN * H * 2);
  unsigned short* hbuf  = (unsigned short*)alloc((size_t)2 * BATCH * H * 2);
  unsigned short* hhist = (unsigned short*)alloc((size_t)TLEN * BATCH * H * 2);
  unsigned int*   flags = (unsigned int*)  alloc((size_t)NBLK * 16 * sizeof(unsigned));
  (void)ws_size; (void)in_sizes; (void)n_in; (void)out_size;

  hipMemsetAsync(flags, 0, (size_t)NBLK * 16 * sizeof(unsigned), stream);
  hipLaunchKernelGGL(k_convert, dim3(512), dim3(256), 0, stream, input_batch, xin, SEQ * BATCH * IN);
  hipLaunchKernelGGL(k_convert, dim3(64),  dim3(256), 0, stream, linW, linbf, IN * H);
  hipLaunchKernelGGL(k_pack,   dim3(G4), dim3(256), 0, stream, eWih, eWhh, ebih, ebhh, Wenc, benc);
  hipLaunchKernelGGL(k_pack,   dim3(G4), dim3(256), 0, stream, dWih, dWhh, dbih, dbhh, Wdec0, bdec0);
  hipLaunchKernelGGL(k_deceff, dim3(G4), dim3(256), 0, stream, dWih, dWhh, dbih, dbhh, linW, linb, Wdeff, bdeff);

  void* args[] = { &xin, &Wenc, &benc, &Wdec0, &bdec0, &Wdeff, &bdeff, &hbuf, &hhist, &flags };
  hipLaunchCooperativeKernel((void*)k_lstm, dim3(NBLK), dim3(512), args, 0, stream);

  hipLaunchKernelGGL(k_out, dim3((TLEN * BATCH) / 64), dim3(256), 0, stream, hhist, linbf, linb, out);
}

// Round 4
// 4397.092 us; speedup vs baseline: 3.0903x; 1.5073x over previous
//
#include <hip/hip_runtime.h>
#include <stdint.h>

#define IN    64
#define H     1024
#define G4    4096      // 4*H gate rows
#define BATCH 128
#define SEQ   256
#define TLEN  96
#define KCAT  1088      // IN + H
#define NSTEP (SEQ + TLEN)
#define NBLK  256
#define HPAD  1032      // h row stride in LDS (bf16), +8 pad
#define ZPAD  132       // z row stride in LDS (f32), +4 pad

typedef __attribute__((ext_vector_type(8))) short bf16x8;
typedef __attribute__((ext_vector_type(4))) float f32x4;

__device__ __forceinline__ unsigned short f2bf(float f) {
  union { float f; uint32_t u; } v; v.f = f;
  uint32_t u = v.u;
  return (unsigned short)((u + 0x7fffu + ((u >> 16) & 1u)) >> 16);  // RNE
}

// global->LDS direct copy, 16B/lane, aux=1 (SC0: bypass L1 so same-XCD L2 dirty
// lines from other CUs are always observed). LDS dest = wave-uniform base + lane*16.
__device__ __forceinline__ void gload_lds16_sc0(const unsigned short* g, unsigned short* l) {
  __builtin_amdgcn_global_load_lds((const __attribute__((address_space(1))) unsigned int*)g,
                                   (__attribute__((address_space(3))) unsigned int*)l, 16, 0, 1);
}

// ---------- generic fp32 -> bf16 ----------
__global__ void k_convert(const float* __restrict__ src, unsigned short* __restrict__ dst, int n) {
  int i = blockIdx.x * blockDim.x + threadIdx.x;
  int stride = gridDim.x * blockDim.x;
  for (; i < n; i += stride) dst[i] = f2bf(src[i]);
}

// ---------- pack [Wih | Whh] gate-interleaved: packed row p=4j+g <-> torch row r=g*H+j ----------
__global__ void k_pack(const float* __restrict__ Wih, const float* __restrict__ Whh,
                       const float* __restrict__ bih, const float* __restrict__ bhh,
                       unsigned short* __restrict__ Wcat, float* __restrict__ bcat) {
  int p = blockIdx.x;                    // 0..4095
  int j = p >> 2, g = p & 3;
  int r = g * H + j;
  for (int c = threadIdx.x; c < KCAT; c += blockDim.x) {
    float v = (c < IN) ? Wih[r * IN + c] : Whh[r * H + (c - IN)];
    Wcat[(size_t)p * KCAT + c] = f2bf(v);
  }
  if (threadIdx.x == 0) bcat[p] = bih[r] + bhh[r];
}

// ---------- decoder fused weights: W_eff = Whh + Wih@lin ; b_eff = bih+bhh+Wih@lin_b ----------
__global__ void k_deceff(const float* __restrict__ Wih, const float* __restrict__ Whh,
                         const float* __restrict__ bih, const float* __restrict__ bhh,
                         const float* __restrict__ lin, const float* __restrict__ linb,
                         unsigned short* __restrict__ Weff, float* __restrict__ beff) {
  int p = blockIdx.x;
  int j = p >> 2, g = p & 3;
  int r = g * H + j;
  __shared__ float wr[IN];
  if (threadIdx.x < IN) wr[threadIdx.x] = Wih[r * IN + threadIdx.x];
  __syncthreads();
  for (int k = threadIdx.x; k < H; k += blockDim.x) {
    float acc = Whh[(size_t)r * H + k];
    #pragma unroll 8
    for (int i = 0; i < IN; ++i) acc += wr[i] * lin[(size_t)i * H + k];
    Weff[(size_t)p * H + k] = f2bf(acc);
  }
  if (threadIdx.x == 0) {
    float s = bih[r] + bhh[r];
    for (int i = 0; i < IN; ++i) s += wr[i] * linb[i];
    beff[p] = s;
  }
}

// ---------- persistent LSTM: XCD-local groups, weights in registers ----------
// 256 blocks x 512 thr, 1 block/CU (forced by 84KB dynamic LDS) -> exactly 32 blocks/XCD
// (cooperative co-residency). Group = physical XCD (runtime s_getreg XCC_ID + ticket):
// owns batch rows [16*xcd, 16*xcd+16); block slot 0..31 owns gates [128*slot, +128).
// Batch rows are recurrence-independent -> barrier is per-XCD (32 blocks), not global.
// h exchange: plain stores -> shared XCD L2; staged back via global_load_lds SC0.
// Weights: 34 bf16x8 frags (136 VGPR) per wave, loaded at t=0 / t=SEQ / t=SEQ+1 only.
__global__ __launch_bounds__(512, 2) void k_lstm(
    const unsigned short* __restrict__ xin,
    const unsigned short* __restrict__ Wenc,  const float* __restrict__ benc,
    const unsigned short* __restrict__ Wdec0, const float* __restrict__ bdec0,
    const unsigned short* __restrict__ Wdeff, const float* __restrict__ bdeff,
    unsigned short* __restrict__ hbuf, unsigned short* __restrict__ hhist,
    unsigned int* __restrict__ flags, unsigned int* __restrict__ tickets)
{
  extern __shared__ char smem[];
  unsigned short* hs = (unsigned short*)smem;              // 16 x HPAD bf16 = 33024 B
  float*          zs = (float*)(smem + 16 * HPAD * 2);     // 16 x ZPAD f32 = 8448 B
  __shared__ int s_xcd, s_slot;
  const int tid  = threadIdx.x;
  const int lane = tid & 63;
  const int wave = tid >> 6;             // 0..7
  if (tid == 0) {
    unsigned x;
    asm volatile("s_getreg_b32 %0, hwreg(HW_REG_XCC_ID)" : "=s"(x));
    x &= 7;
    unsigned tk = __hip_atomic_fetch_add(&tickets[x], 1u, __ATOMIC_RELAXED, __HIP_MEMORY_SCOPE_AGENT);
    s_xcd = (int)x; s_slot = (int)(tk & 31);
  }
  __syncthreads();
  const int grp  = s_xcd;                // row-group == physical XCD
  const int slot = s_slot;               // col slot 0..31
  const int m0   = grp * 16;             // batch rows
  const int n0   = slot * 128;           // gate cols
  const int gw   = n0 + wave * 16;       // this wave's 16 gates
  const int fm   = lane & 15;
  const int fk   = (lane >> 4) * 8;
  const int crow = tid >> 5;             // cell: batch row 0..15
  const int ul   = tid & 31;             // cell: unit-local 0..31
  const unsigned int* myflags = flags + (size_t)grp * 32 * 16;

  bf16x8 B[34];                          // [0..31] h-part K-tiles, [32..33] x-part
  float cst = 0.f;
  int p = 0;
  for (int t = 0; t < NSTEP; ++t) {
    const bool is_enc = (t < SEQ);
    // ---- rare uniform weight (re)loads into registers ----
    if (t == 0 || t == SEQ) {
      const unsigned short* W = (t == 0) ? Wenc : Wdec0;
      const unsigned short* wr = W + (size_t)(gw + fm) * KCAT + fk;
      #pragma unroll
      for (int kt = 0; kt < 32; ++kt) B[kt] = *(const bf16x8*)(wr + IN + kt * 32);
      B[32] = *(const bf16x8*)(wr);
      B[33] = *(const bf16x8*)(wr + 32);
    } else if (t == SEQ + 1) {
      const unsigned short* wr = Wdeff + (size_t)(gw + fm) * H + fk;
      #pragma unroll
      for (int kt = 0; kt < 32; ++kt) B[kt] = *(const bf16x8*)(wr + kt * 32);
    }
    const float* bias = is_enc ? benc : (t == SEQ ? bdec0 : bdeff);
    const unsigned short* xsrc =
        is_enc ? xin + (size_t)t * BATCH * IN
               : (t == SEQ ? xin + (size_t)(SEQ - 1) * BATCH * IN : nullptr);
    // ---- stage h(t) rows (16 x 1024 bf16 = 32 KB) from XCD L2 into LDS ----
    if (t > 0) {
      const unsigned short* hb = hbuf + (size_t)p * BATCH * H + (size_t)m0 * H;
      #pragma unroll
      for (int j = 0; j < 4; ++j) {
        int row  = wave * 2 + (j >> 1);
        int half = (j & 1) * 512;
        gload_lds16_sc0(hb + (size_t)row * H + half + lane * 8, &hs[row * HPAD + half]);
      }
    }
    __syncthreads();   // staging complete (vmcnt drained before s_barrier)
    // ---- K-loop: A from LDS, B from registers ----
    f32x4 acc = {0.f, 0.f, 0.f, 0.f};
    if (t > 0) {
      const unsigned short* as = &hs[fm * HPAD + fk];
      #pragma unroll
      for (int kt = 0; kt < 32; ++kt)
        acc = __builtin_amdgcn_mfma_f32_16x16x32_bf16(*(const bf16x8*)(as + kt * 32), B[kt], acc, 0, 0, 0);
    }
    if (xsrc) {
      const unsigned short* xa = xsrc + (size_t)(m0 + fm) * IN + fk;
      acc = __builtin_amdgcn_mfma_f32_16x16x32_bf16(*(const bf16x8*)(xa),      B[32], acc, 0, 0, 0);
      acc = __builtin_amdgcn_mfma_f32_16x16x32_bf16(*(const bf16x8*)(xa + 32), B[33], acc, 0, 0, 0);
    }
    // ---- scatter z (D layout: col=lane&15, row=(lane>>4)*4+reg) ----
    {
      int colz = wave * 16 + fm;
      int rb   = (lane >> 4) * 4;
      #pragma unroll
      for (int j = 0; j < 4; ++j) zs[(rb + j) * ZPAD + colz] = acc[j];
    }
    __syncthreads();
    // ---- fused LSTM cell: 1 (row, unit) per thread; gates i,f,g,o adjacent ----
    {
      const float4 z4 = *(const float4*)&zs[crow * ZPAD + 4 * ul];
      const float4 b4 = *(const float4*)&bias[n0 + 4 * ul];
      float zi = z4.x + b4.x, zf = z4.y + b4.y, zg = z4.z + b4.z, zo = z4.w + b4.w;
      float gi = 1.f / (1.f + __expf(-zi));
      float gf = 1.f / (1.f + __expf(-zf));
      float gg = tanhf(zg);
      float go = 1.f / (1.f + __expf(-zo));
      float c  = gf * cst + gi * gg;
      cst = c;
      float h = go * tanhf(c);
      unsigned short hb16 = f2bf(h);
      size_t idx = (size_t)(m0 + crow) * H + (n0 >> 2) + ul;
      hbuf[(size_t)(1 - p) * BATCH * H + idx] = hb16;            // plain store -> XCD L2
      if (!is_enc) hhist[(size_t)(t - SEQ) * BATCH * H + idx] = hb16;
    }
    p ^= 1;
    // ---- XCD-local epoch barrier over 32 blocks ----
    if (t + 1 < NSTEP) {
      __syncthreads();   // drains all waves' h stores into L2 before flag
      if (tid == 0)
        __hip_atomic_store(&flags[((size_t)grp * 32 + slot) * 16], (unsigned)(t + 1),
                           __ATOMIC_RELAXED, __HIP_MEMORY_SCOPE_AGENT);
      if (tid < 32) {
        while (__hip_atomic_load(&myflags[tid * 16], __ATOMIC_RELAXED, __HIP_MEMORY_SCOPE_AGENT) < (unsigned)(t + 1))
          __builtin_amdgcn_s_sleep(1);
      }
      __syncthreads();
    }
  }
}

// ---------- epilogue: all 96 outputs in one GEMM  y = hhist @ lin^T + lin_b ----------
__global__ __launch_bounds__(256) void k_out(
    const unsigned short* __restrict__ hhist, const unsigned short* __restrict__ linb16,
    const float* __restrict__ linb, float* __restrict__ out)
{
  const int tid  = threadIdx.x;
  const int lane = tid & 63;
  const int wave = tid >> 6;
  const int fm   = lane & 15;
  const int fk   = (lane >> 4) * 8;
  const int R0   = blockIdx.x * 64 + wave * 16;
  f32x4 acc[4] = {{0.f,0.f,0.f,0.f},{0.f,0.f,0.f,0.f},{0.f,0.f,0.f,0.f},{0.f,0.f,0.f,0.f}};
  const unsigned short* ha = hhist + (size_t)(R0 + fm) * H + fk;
  #pragma unroll 2
  for (int kc = 0; kc < H; kc += 32) {
    bf16x8 a = *(const bf16x8*)(ha + kc);
    #pragma unroll
    for (int nq = 0; nq < 4; ++nq) {
      bf16x8 b = *(const bf16x8*)(linb16 + (size_t)(nq * 16 + fm) * H + fk + kc);
      acc[nq] = __builtin_amdgcn_mfma_f32_16x16x32_bf16(a, b, acc[nq], 0, 0, 0);
    }
  }
  #pragma unroll
  for (int nq = 0; nq < 4; ++nq) {
    int col = nq * 16 + fm;
    float bb = linb[col];
    #pragma unroll
    for (int j = 0; j < 4; ++j) {
      int R = R0 + (lane >> 4) * 4 + j;
      out[(size_t)R * IN + col] = acc[nq][j] + bb;
    }
  }
}

extern "C" void kernel_launch(void* const* d_in, const int* in_sizes, int n_in,
                              void* d_out, int out_size, void* d_ws, size_t ws_size,
                              hipStream_t stream) {
  const float* input_batch = (const float*)d_in[0];
  // d_in[1] target_batch: unused (no teacher forcing)
  const float* eWih = (const float*)d_in[2];
  const float* eWhh = (const float*)d_in[3];
  const float* ebih = (const float*)d_in[4];
  const float* ebhh = (const float*)d_in[5];
  const float* dWih = (const float*)d_in[6];
  const float* dWhh = (const float*)d_in[7];
  const float* dbih = (const float*)d_in[8];
  const float* dbhh = (const float*)d_in[9];
  const float* linW = (const float*)d_in[10];
  const float* linb = (const float*)d_in[11];
  float* out = (float*)d_out;

  char* ws = (char*)d_ws;
  size_t off = 0;
  auto alloc = [&](size_t bytes) -> void* {
    void* pp = ws + off;
    off = (off + bytes + 255) & ~(size_t)255;
    return pp;
  };
  unsigned short* xin   = (unsigned short*)alloc((size_t)SEQ * BATCH * IN * 2);
  unsigned short* Wenc  = (unsigned short*)alloc((size_t)G4 * KCAT * 2);
  float*          benc  = (float*)         alloc((size_t)G4 * 4);
  unsigned short* Wdec0 = (unsigned short*)alloc((size_t)G4 * KCAT * 2);
  float*          bdec0 = (float*)         alloc((size_t)G4 * 4);
  unsigned short* Wdeff = (unsigned short*)alloc((size_t)G4 * H * 2);
  float*          bdeff = (float*)         alloc((size_t)G4 * 4);
  unsigned short* linbf = (unsigned short*)alloc((size_t)IN * H * 2);
  unsigned short* hbuf  = (unsigned short*)alloc((size_t)2 * BATCH * H * 2);
  unsigned short* hhist = (unsigned short*)alloc((size_t)TLEN * BATCH * H * 2);
  unsigned int*   flags = (unsigned int*)  alloc((size_t)8 * 32 * 16 * sizeof(unsigned));
  unsigned int*   tickets = (unsigned int*)alloc((size_t)8 * sizeof(unsigned));
  (void)ws_size; (void)in_sizes; (void)n_in; (void)out_size;

  hipMemsetAsync(flags, 0, (size_t)8 * 32 * 16 * sizeof(unsigned), stream);
  hipMemsetAsync(tickets, 0, (size_t)8 * sizeof(unsigned), stream);
  hipLaunchKernelGGL(k_convert, dim3(512), dim3(256), 0, stream, input_batch, xin, SEQ * BATCH * IN);
  hipLaunchKernelGGL(k_convert, dim3(64),  dim3(256), 0, stream, linW, linbf, IN * H);
  hipLaunchKernelGGL(k_pack,   dim3(G4), dim3(256), 0, stream, eWih, eWhh, ebih, ebhh, Wenc, benc);
  hipLaunchKernelGGL(k_pack,   dim3(G4), dim3(256), 0, stream, dWih, dWhh, dbih, dbhh, Wdec0, bdec0);
  hipLaunchKernelGGL(k_deceff, dim3(G4), dim3(256), 0, stream, dWih, dWhh, dbih, dbhh, linW, linb, Wdeff, bdeff);

  void* args[] = { &xin, &Wenc, &benc, &Wdec0, &bdec0, &Wdeff, &bdeff, &hbuf, &hhist, &flags, &tickets };
  hipLaunchCooperativeKernel((void*)k_lstm, dim3(NBLK), dim3(512), args, 86016, stream);

  hipLaunchKernelGGL(k_out, dim3((TLEN * BATCH) / 64), dim3(256), 0, stream, hhist, linbf, linb, out);
}

// Round 7
// 4352.962 us; speedup vs baseline: 3.1217x; 1.0101x over previous
//
#include <hip/hip_runtime.h>
#include <stdint.h>

#define IN    64
#define H     1024
#define G4    4096      // 4*H gate rows
#define BATCH 128
#define SEQ   256
#define TLEN  96
#define KCAT  1088      // IN + H
#define NSTEP (SEQ + TLEN)
#define NBLK  256
#define HPAD  1032      // h row stride in LDS (bf16), +8 pad
#define ZPAD  132       // z row stride in LDS (f32), +4 pad

typedef __attribute__((ext_vector_type(8))) short bf16x8;
typedef __attribute__((ext_vector_type(4))) float f32x4;

__device__ __forceinline__ unsigned short f2bf(float f) {
  union { float f; uint32_t u; } v; v.f = f;
  uint32_t u = v.u;
  return (unsigned short)((u + 0x7fffu + ((u >> 16) & 1u)) >> 16);  // RNE
}

// global->LDS direct copy, 16B/lane, aux=1 (SC0: bypass L1 so same-XCD L2 dirty
// lines from other CUs are observed). LDS dest = wave-uniform base + lane*16.
__device__ __forceinline__ void gload_lds16_sc0(const unsigned short* g, unsigned short* l) {
  __builtin_amdgcn_global_load_lds((const __attribute__((address_space(1))) unsigned int*)g,
                                   (__attribute__((address_space(3))) unsigned int*)l, 16, 0, 1);
}

// ---------- generic fp32 -> bf16 ----------
__global__ void k_convert(const float* __restrict__ src, unsigned short* __restrict__ dst, int n) {
  int i = blockIdx.x * blockDim.x + threadIdx.x;
  int stride = gridDim.x * blockDim.x;
  for (; i < n; i += stride) dst[i] = f2bf(src[i]);
}

// ---------- pack [Wih | Whh] gate-interleaved: packed row p=4j+g <-> torch row r=g*H+j ----------
__global__ void k_pack(const float* __restrict__ Wih, const float* __restrict__ Whh,
                       const float* __restrict__ bih, const float* __restrict__ bhh,
                       unsigned short* __restrict__ Wcat, float* __restrict__ bcat) {
  int p = blockIdx.x;                    // 0..4095
  int j = p >> 2, g = p & 3;
  int r = g * H + j;
  for (int c = threadIdx.x; c < KCAT; c += blockDim.x) {
    float v = (c < IN) ? Wih[r * IN + c] : Whh[r * H + (c - IN)];
    Wcat[(size_t)p * KCAT + c] = f2bf(v);
  }
  if (threadIdx.x == 0) bcat[p] = bih[r] + bhh[r];
}

// ---------- decoder fused weights: W_eff = Whh + Wih@lin ; b_eff = bih+bhh+Wih@lin_b ----------
__global__ void k_deceff(const float* __restrict__ Wih, const float* __restrict__ Whh,
                         const float* __restrict__ bih, const float* __restrict__ bhh,
                         const float* __restrict__ lin, const float* __restrict__ linb,
                         unsigned short* __restrict__ Weff, float* __restrict__ beff) {
  int p = blockIdx.x;
  int j = p >> 2, g = p & 3;
  int r = g * H + j;
  __shared__ float wr[IN];
  if (threadIdx.x < IN) wr[threadIdx.x] = Wih[r * IN + threadIdx.x];
  __syncthreads();
  for (int k = threadIdx.x; k < H; k += blockDim.x) {
    float acc = Whh[(size_t)r * H + k];
    #pragma unroll 8
    for (int i = 0; i < IN; ++i) acc += wr[i] * lin[(size_t)i * H + k];
    Weff[(size_t)p * H + k] = f2bf(acc);
  }
  if (threadIdx.x == 0) {
    float s = bih[r] + bhh[r];
    for (int i = 0; i < IN; ++i) s += wr[i] * linb[i];
    beff[p] = s;
  }
}

// ---------- persistent LSTM: XCD-local groups, weights in registers ----------
// Structure identical to the PASSING Round-4 kernel. Single delta: the per-group
// 32 barrier flags are packed into 128 B (2 cachelines) instead of 32 lines, so
// the tid<32 gather poll coalesces into 1-2 MALL transactions per round instead
// of a 32-line walk. Primitives unchanged: agent-scope atomic store/load +
// s_sleep(1) backoff (backoff-free polling suspected of RMW-starvation livelock
// in R5/R6).
__global__ __launch_bounds__(512, 2) void k_lstm(
    const unsigned short* __restrict__ xin,
    const unsigned short* __restrict__ Wenc,  const float* __restrict__ benc,
    const unsigned short* __restrict__ Wdec0, const float* __restrict__ bdec0,
    const unsigned short* __restrict__ Wdeff, const float* __restrict__ bdeff,
    unsigned short* __restrict__ hbuf, unsigned short* __restrict__ hhist,
    unsigned int* __restrict__ flags, unsigned int* __restrict__ tickets)
{
  extern __shared__ char smem[];
  unsigned short* hs = (unsigned short*)smem;              // 16 x HPAD bf16 = 33024 B
  float*          zs = (float*)(smem + 16 * HPAD * 2);     // 16 x ZPAD f32 = 8448 B
  __shared__ int s_xcd, s_slot;
  const int tid  = threadIdx.x;
  const int lane = tid & 63;
  const int wave = tid >> 6;             // 0..7
  if (tid == 0) {
    unsigned x;
    asm volatile("s_getreg_b32 %0, hwreg(HW_REG_XCC_ID)" : "=s"(x));
    x &= 7;
    unsigned tk = __hip_atomic_fetch_add(&tickets[x], 1u, __ATOMIC_RELAXED, __HIP_MEMORY_SCOPE_AGENT);
    s_xcd = (int)x; s_slot = (int)(tk & 31);
  }
  __syncthreads();
  const int grp  = s_xcd;                // row-group == physical XCD
  const int slot = s_slot;               // col slot 0..31
  const int m0   = grp * 16;             // batch rows
  const int n0   = slot * 128;           // gate cols
  const int gw   = n0 + wave * 16;       // this wave's 16 gates
  const int fm   = lane & 15;
  const int fk   = (lane >> 4) * 8;
  const int crow = tid >> 5;             // cell: batch row 0..15
  const int ul   = tid & 31;             // cell: unit-local 0..31
  const unsigned int* myflags = flags + (size_t)grp * 32;   // PACKED: 32 x 4B = 128 B

  bf16x8 B[34];                          // [0..31] h-part K-tiles, [32..33] x-part
  float cst = 0.f;
  int p = 0;
  for (int t = 0; t < NSTEP; ++t) {
    const bool is_enc = (t < SEQ);
    // ---- rare uniform weight (re)loads into registers ----
    if (t == 0 || t == SEQ) {
      const unsigned short* W = (t == 0) ? Wenc : Wdec0;
      const unsigned short* wr = W + (size_t)(gw + fm) * KCAT + fk;
      #pragma unroll
      for (int kt = 0; kt < 32; ++kt) B[kt] = *(const bf16x8*)(wr + IN + kt * 32);
      B[32] = *(const bf16x8*)(wr);
      B[33] = *(const bf16x8*)(wr + 32);
    } else if (t == SEQ + 1) {
      const unsigned short* wr = Wdeff + (size_t)(gw + fm) * H + fk;
      #pragma unroll
      for (int kt = 0; kt < 32; ++kt) B[kt] = *(const bf16x8*)(wr + kt * 32);
    }
    const float* bias = is_enc ? benc : (t == SEQ ? bdec0 : bdeff);
    const unsigned short* xsrc =
        is_enc ? xin + (size_t)t * BATCH * IN
               : (t == SEQ ? xin + (size_t)(SEQ - 1) * BATCH * IN : nullptr);
    // ---- stage h(t) rows (16 x 1024 bf16 = 32 KB) from XCD L2 into LDS ----
    if (t > 0) {
      const unsigned short* hb = hbuf + (size_t)p * BATCH * H + (size_t)m0 * H;
      #pragma unroll
      for (int j = 0; j < 4; ++j) {
        int row  = wave * 2 + (j >> 1);
        int half = (j & 1) * 512;
        gload_lds16_sc0(hb + (size_t)row * H + half + lane * 8, &hs[row * HPAD + half]);
      }
    }
    __syncthreads();   // staging complete (vmcnt drained before s_barrier)
    // ---- K-loop: A from LDS, B from registers ----
    f32x4 acc = {0.f, 0.f, 0.f, 0.f};
    if (t > 0) {
      const unsigned short* as = &hs[fm * HPAD + fk];
      #pragma unroll
      for (int kt = 0; kt < 32; ++kt)
        acc = __builtin_amdgcn_mfma_f32_16x16x32_bf16(*(const bf16x8*)(as + kt * 32), B[kt], acc, 0, 0, 0);
    }
    if (xsrc) {
      const unsigned short* xa = xsrc + (size_t)(m0 + fm) * IN + fk;
      acc = __builtin_amdgcn_mfma_f32_16x16x32_bf16(*(const bf16x8*)(xa),      B[32], acc, 0, 0, 0);
      acc = __builtin_amdgcn_mfma_f32_16x16x32_bf16(*(const bf16x8*)(xa + 32), B[33], acc, 0, 0, 0);
    }
    // ---- scatter z (D layout: col=lane&15, row=(lane>>4)*4+reg) ----
    {
      int colz = wave * 16 + fm;
      int rb   = (lane >> 4) * 4;
      #pragma unroll
      for (int j = 0; j < 4; ++j) zs[(rb + j) * ZPAD + colz] = acc[j];
    }
    __syncthreads();
    // ---- fused LSTM cell: 1 (row, unit) per thread; gates i,f,g,o adjacent ----
    {
      const float4 z4 = *(const float4*)&zs[crow * ZPAD + 4 * ul];
      const float4 b4 = *(const float4*)&bias[n0 + 4 * ul];
      float zi = z4.x + b4.x, zf = z4.y + b4.y, zg = z4.z + b4.z, zo = z4.w + b4.w;
      float gi = 1.f / (1.f + __expf(-zi));
      float gf = 1.f / (1.f + __expf(-zf));
      float gg = tanhf(zg);
      float go = 1.f / (1.f + __expf(-zo));
      float c  = gf * cst + gi * gg;
      cst = c;
      float h = go * tanhf(c);
      unsigned short hb16 = f2bf(h);
      size_t idx = (size_t)(m0 + crow) * H + (n0 >> 2) + ul;
      hbuf[(size_t)(1 - p) * BATCH * H + idx] = hb16;            // plain store -> XCD L2
      if (!is_enc) hhist[(size_t)(t - SEQ) * BATCH * H + idx] = hb16;
    }
    p ^= 1;
    // ---- XCD-local epoch barrier over 32 blocks (flags packed in 2 lines) ----
    if (t + 1 < NSTEP) {
      __syncthreads();   // drains all waves' h stores into L2 before flag
      if (tid == 0)
        __hip_atomic_store(&flags[grp * 32 + slot], (unsigned)(t + 1),
                           __ATOMIC_RELAXED, __HIP_MEMORY_SCOPE_AGENT);
      if (tid < 32) {
        while (__hip_atomic_load(&myflags[tid], __ATOMIC_RELAXED, __HIP_MEMORY_SCOPE_AGENT) < (unsigned)(t + 1))
          __builtin_amdgcn_s_sleep(1);
      }
      __syncthreads();
    }
  }
}

// ---------- epilogue: all 96 outputs in one GEMM  y = hhist @ lin^T + lin_b ----------
__global__ __launch_bounds__(256) void k_out(
    const unsigned short* __restrict__ hhist, const unsigned short* __restrict__ linb16,
    const float* __restrict__ linb, float* __restrict__ out)
{
  const int tid  = threadIdx.x;
  const int lane = tid & 63;
  const int wave = tid >> 6;
  const int fm   = lane & 15;
  const int fk   = (lane >> 4) * 8;
  const int R0   = blockIdx.x * 64 + wave * 16;
  f32x4 acc[4] = {{0.f,0.f,0.f,0.f},{0.f,0.f,0.f,0.f},{0.f,0.f,0.f,0.f},{0.f,0.f,0.f,0.f}};
  const unsigned short* ha = hhist + (size_t)(R0 + fm) * H + fk;
  #pragma unroll 2
  for (int kc = 0; kc < H; kc += 32) {
    bf16x8 a = *(const bf16x8*)(ha + kc);
    #pragma unroll
    for (int nq = 0; nq < 4; ++nq) {
      bf16x8 b = *(const bf16x8*)(linb16 + (size_t)(nq * 16 + fm) * H + fk + kc);
      acc[nq] = __builtin_amdgcn_mfma_f32_16x16x32_bf16(a, b, acc[nq], 0, 0, 0);
    }
  }
  #pragma unroll
  for (int nq = 0; nq < 4; ++nq) {
    int col = nq * 16 + fm;
    float bb = linb[col];
    #pragma unroll
    for (int j = 0; j < 4; ++j) {
      int R = R0 + (lane >> 4) * 4 + j;
      out[(size_t)R * IN + col] = acc[nq][j] + bb;
    }
  }
}

extern "C" void kernel_launch(void* const* d_in, const int* in_sizes, int n_in,
                              void* d_out, int out_size, void* d_ws, size_t ws_size,
                              hipStream_t stream) {
  const float* input_batch = (const float*)d_in[0];
  // d_in[1] target_batch: unused (no teacher forcing)
  const float* eWih = (const float*)d_in[2];
  const float* eWhh = (const float*)d_in[3];
  const float* ebih = (const float*)d_in[4];
  const float* ebhh = (const float*)d_in[5];
  const float* dWih = (const float*)d_in[6];
  const float* dWhh = (const float*)d_in[7];
  const float* dbih = (const float*)d_in[8];
  const float* dbhh = (const float*)d_in[9];
  const float* linW = (const float*)d_in[10];
  const float* linb = (const float*)d_in[11];
  float* out = (float*)d_out;

  char* ws = (char*)d_ws;
  size_t off = 0;
  auto alloc = [&](size_t bytes) -> void* {
    void* pp = ws + off;
    off = (off + bytes + 255) & ~(size_t)255;
    return pp;
  };
  unsigned short* xin   = (unsigned short*)alloc((size_t)SEQ * BATCH * IN * 2);
  unsigned short* Wenc  = (unsigned short*)alloc((size_t)G4 * KCAT * 2);
  float*          benc  = (float*)         alloc((size_t)G4 * 4);
  unsigned short* Wdec0 = (unsigned short*)alloc((size_t)G4 * KCAT * 2);
  float*          bdec0 = (float*)         alloc((size_t)G4 * 4);
  unsigned short* Wdeff = (unsigned short*)alloc((size_t)G4 * H * 2);
  float*          bdeff = (float*)         alloc((size_t)G4 * 4);
  unsigned short* linbf = (unsigned short*)alloc((size_t)IN * H * 2);
  unsigned short* hbuf  = (unsigned short*)alloc((size_t)2 * BATCH * H * 2);
  unsigned short* hhist = (unsigned short*)alloc((size_t)TLEN * BATCH * H * 2);
  unsigned int*   flags = (unsigned int*)  alloc((size_t)8 * 32 * sizeof(unsigned));
  unsigned int*   tickets = (unsigned int*)alloc((size_t)8 * sizeof(unsigned));
  (void)ws_size; (void)in_sizes; (void)n_in; (void)out_size;

  hipMemsetAsync(flags, 0, (size_t)8 * 32 * sizeof(unsigned), stream);
  hipMemsetAsync(tickets, 0, (size_t)8 * sizeof(unsigned), stream);
  hipLaunchKernelGGL(k_convert, dim3(512), dim3(256), 0, stream, input_batch, xin, SEQ * BATCH * IN);
  hipLaunchKernelGGL(k_convert, dim3(64),  dim3(256), 0, stream, linW, linbf, IN * H);
  hipLaunchKernelGGL(k_pack,   dim3(G4), dim3(256), 0, stream, eWih, eWhh, ebih, ebhh, Wenc, benc);
  hipLaunchKernelGGL(k_pack,   dim3(G4), dim3(256), 0, stream, dWih, dWhh, dbih, dbhh, Wdec0, bdec0);
  hipLaunchKernelGGL(k_deceff, dim3(G4), dim3(256), 0, stream, dWih, dWhh, dbih, dbhh, linW, linb, Wdeff, bdeff);

  void* args[] = { &xin, &Wenc, &benc, &Wdec0, &bdec0, &Wdeff, &bdeff, &hbuf, &hhist, &flags, &tickets };
  hipLaunchCooperativeKernel((void*)k_lstm, dim3(NBLK), dim3(512), args, 86016, stream);

  hipLaunchKernelGGL(k_out, dim3((TLEN * BATCH) / 64), dim3(256), 0, stream, hhist, linbf, linb, out);
}